// Round 1
// baseline (576.145 us; speedup 1.0000x reference)
//
#include <hip/hip_runtime.h>
#include <hip/hip_bf16.h>

// Problem constants: B=32, S=512, D=256, H=8, DH=32
#define SCALE_QK 0.17677669529663687f  // 1/sqrt(32)

__device__ __forceinline__ void waveRed2(float &a, float &b) {
#pragma unroll
  for (int off = 32; off > 0; off >>= 1) {
    a += __shfl_xor(a, off, 64);
    b += __shfl_xor(b, off, 64);
  }
}

// C[m,n] = sum_k A[m,k]*W[n,k] + bias[n];  M=16384, N=256, K=256
// mode 0: C stored row-major [m][n] (i.e. [B,S,256])
// mode 1: C stored as q/k layout [b,h,s,e]: b=m>>9, s=m&511, h=n>>5, e=n&31
__global__ __launch_bounds__(256) void gemm_proj(const float *__restrict__ A,
                                                 const float *__restrict__ W,
                                                 const float *__restrict__ bias,
                                                 float *__restrict__ C,
                                                 int mode) {
  __shared__ float As[16][68];
  __shared__ float Ws[16][68];
  const int tid = threadIdx.x;
  const int m0 = blockIdx.x * 64;
  const int n0 = blockIdx.y * 64;
  const int ty = tid >> 4, tx = tid & 15;
  const int lm = tid >> 2, lk4 = (tid & 3) * 4;
  const float *Ald = A + (m0 + lm) * 256 + lk4;
  const float *Wld = W + (n0 + lm) * 256 + lk4;
  float acc[4][4] = {};
  for (int k0 = 0; k0 < 256; k0 += 16) {
    const float4 av = *(const float4 *)(Ald + k0);
    const float4 wv = *(const float4 *)(Wld + k0);
    __syncthreads();
    As[lk4 + 0][lm] = av.x; As[lk4 + 1][lm] = av.y;
    As[lk4 + 2][lm] = av.z; As[lk4 + 3][lm] = av.w;
    Ws[lk4 + 0][lm] = wv.x; Ws[lk4 + 1][lm] = wv.y;
    Ws[lk4 + 2][lm] = wv.z; Ws[lk4 + 3][lm] = wv.w;
    __syncthreads();
#pragma unroll
    for (int kk = 0; kk < 16; ++kk) {
      const float4 a = *(const float4 *)&As[kk][ty * 4];
      const float4 w = *(const float4 *)&Ws[kk][tx * 4];
      const float ar[4] = {a.x, a.y, a.z, a.w};
      const float wr[4] = {w.x, w.y, w.z, w.w};
#pragma unroll
      for (int r = 0; r < 4; ++r)
#pragma unroll
        for (int c = 0; c < 4; ++c) acc[r][c] += ar[r] * wr[c];
    }
  }
  const float4 bs = *(const float4 *)(bias + n0 + tx * 4);
  const float br[4] = {bs.x, bs.y, bs.z, bs.w};
#pragma unroll
  for (int r = 0; r < 4; ++r) {
    const int m = m0 + ty * 4 + r;
    float4 o;
    o.x = acc[r][0] + br[0]; o.y = acc[r][1] + br[1];
    o.z = acc[r][2] + br[2]; o.w = acc[r][3] + br[3];
    if (mode == 0) {
      *(float4 *)(C + m * 256 + n0 + tx * 4) = o;
    } else {
      const int b = m >> 9, s = m & 511;
      const int n = n0 + tx * 4, h = n >> 5, e = n & 31;
      *(float4 *)(C + (((b << 3) + h) * 512 + s) * 32 + e) = o;
    }
  }
}

// Fused scores + diag-mask + sparsemax + head-average.
// Q,K layout [B,H,S,32]. avg output [B,S,S] (already includes the 1/H).
// Block: (s-tile of 16 rows, b). 256 threads = 4 waves; wave w owns rows
// 4w..4w+3; lane l owns t in {4l..4l+3} U {256+4l..256+4l+3} -> each lane
// holds exactly the 8 score elements per row needed for wave-level sparsemax.
__global__ __launch_bounds__(256) void attn_sparsemax(
    const float *__restrict__ Q, const float *__restrict__ Kmat,
    float *__restrict__ avg) {
  __shared__ float kT[16][516];  // [e-half][t], stride 516 keeps writes ~2-way
  __shared__ float qT[32][20];   // [e][r], pre-scaled by 1/sqrt(32)
  const int tid = threadIdx.x;
  const int s0 = blockIdx.x * 16;
  const int b = blockIdx.y;
  const int wave = tid >> 6, lane = tid & 63;
  float avgacc[4][8] = {};
#pragma unroll 1
  for (int h = 0; h < 8; ++h) {
    const float *qh = Q + (((b << 3) + h) * 512 + s0) * 32;
    const float *kh = Kmat + ((b << 3) + h) * 512 * 32;
    float z[4][8] = {};
#pragma unroll 1
    for (int ph = 0; ph < 2; ++ph) {
      __syncthreads();  // previous LDS consumers done before overwrite
      if (ph == 0 && tid < 128) {
        const float4 v = *(const float4 *)(qh + tid * 4);
        const int r = tid >> 3, e4 = (tid & 7) * 4;
        qT[e4 + 0][r] = v.x * SCALE_QK;
        qT[e4 + 1][r] = v.y * SCALE_QK;
        qT[e4 + 2][r] = v.z * SCALE_QK;
        qT[e4 + 3][r] = v.w * SCALE_QK;
      }
#pragma unroll
      for (int i = 0; i < 8; ++i) {
        const int flat4 = i * 256 + tid;
        const int t = flat4 >> 2, e4 = (flat4 & 3) * 4;
        const float4 v = *(const float4 *)(kh + t * 32 + ph * 16 + e4);
        kT[e4 + 0][t] = v.x; kT[e4 + 1][t] = v.y;
        kT[e4 + 2][t] = v.z; kT[e4 + 3][t] = v.w;
      }
      __syncthreads();
#pragma unroll 4
      for (int e = 0; e < 16; ++e) {
        const float4 qv = *(const float4 *)&qT[ph * 16 + e][wave * 4];
        const float4 ka = *(const float4 *)&kT[e][lane * 4];
        const float4 kb = *(const float4 *)&kT[e][256 + lane * 4];
        const float qr[4] = {qv.x, qv.y, qv.z, qv.w};
        const float kv[8] = {ka.x, ka.y, ka.z, ka.w, kb.x, kb.y, kb.z, kb.w};
#pragma unroll
        for (int r = 0; r < 4; ++r)
#pragma unroll
          for (int j = 0; j < 8; ++j) z[r][j] += qr[r] * kv[j];
      }
    }
    // per-row: diag mask, sparsemax (Michelot), accumulate head average
#pragma unroll
    for (int r = 0; r < 4; ++r) {
      const int s = s0 + wave * 4 + r;
#pragma unroll
      for (int j = 0; j < 8; ++j) {
        const int t = (j < 4) ? lane * 4 + j : 256 + lane * 4 + (j - 4);
        if (t == s) z[r][j] = -1e30f;
      }
      float ssum = 0.f, scnt = 0.f;
#pragma unroll
      for (int j = 0; j < 8; ++j) {
        const float zz = z[r][j];
        if (zz > -1e29f) { ssum += zz; scnt += 1.f; }
      }
      waveRed2(ssum, scnt);
      float tau = (ssum - 1.f) / scnt;
      float cnt = scnt;
      for (int it = 0; it < 16; ++it) {
        float ns = 0.f, nc = 0.f;
#pragma unroll
        for (int j = 0; j < 8; ++j) {
          const float zz = z[r][j];
          if (zz > tau) { ns += zz; nc += 1.f; }
        }
        waveRed2(ns, nc);
        if (nc == cnt) break;  // support fixed -> tau is exact
        cnt = nc;
        tau = (ns - 1.f) / nc;
      }
#pragma unroll
      for (int j = 0; j < 8; ++j)
        avgacc[r][j] += fmaxf(z[r][j] - tau, 0.f);
    }
  }
#pragma unroll
  for (int r = 0; r < 4; ++r) {
    const int s = s0 + wave * 4 + r;
    float *dst = avg + ((b * 512 + s) << 9);
    float4 o0, o1;
    o0.x = avgacc[r][0] * 0.125f; o0.y = avgacc[r][1] * 0.125f;
    o0.z = avgacc[r][2] * 0.125f; o0.w = avgacc[r][3] * 0.125f;
    o1.x = avgacc[r][4] * 0.125f; o1.y = avgacc[r][5] * 0.125f;
    o1.z = avgacc[r][6] * 0.125f; o1.w = avgacc[r][7] * 0.125f;
    *(float4 *)(dst + lane * 4) = o0;
    *(float4 *)(dst + 256 + lane * 4) = o1;
  }
}

// Batched NN GEMM: C[b] = A[b] (512x512) * V[b] (512x256)
__global__ __launch_bounds__(256) void gemm_av(const float *__restrict__ A,
                                               const float *__restrict__ V,
                                               float *__restrict__ C) {
  __shared__ float As[16][68];
  __shared__ float Bs[16][68];
  const int tid = threadIdx.x;
  const int b = blockIdx.z;
  const int m0 = blockIdx.x * 64, n0 = blockIdx.y * 64;
  const float *Ab = A + b * 512 * 512;
  const float *Vb = V + b * 512 * 256;
  float *Cb = C + b * 512 * 256;
  const int ty = tid >> 4, tx = tid & 15;
  const int lm = tid >> 2, lk4 = (tid & 3) * 4;
  const int lkb = tid >> 4, lnb = (tid & 15) * 4;
  float acc[4][4] = {};
  for (int k0 = 0; k0 < 512; k0 += 16) {
    const float4 av = *(const float4 *)(Ab + (m0 + lm) * 512 + k0 + lk4);
    const float4 bv = *(const float4 *)(Vb + (k0 + lkb) * 256 + n0 + lnb);
    __syncthreads();
    As[lk4 + 0][lm] = av.x; As[lk4 + 1][lm] = av.y;
    As[lk4 + 2][lm] = av.z; As[lk4 + 3][lm] = av.w;
    *(float4 *)&Bs[lkb][lnb] = bv;
    __syncthreads();
#pragma unroll
    for (int kk = 0; kk < 16; ++kk) {
      const float4 a = *(const float4 *)&As[kk][ty * 4];
      const float4 w = *(const float4 *)&Bs[kk][tx * 4];
      const float ar[4] = {a.x, a.y, a.z, a.w};
      const float wr[4] = {w.x, w.y, w.z, w.w};
#pragma unroll
      for (int r = 0; r < 4; ++r)
#pragma unroll
        for (int c = 0; c < 4; ++c) acc[r][c] += ar[r] * wr[c];
    }
  }
#pragma unroll
  for (int r = 0; r < 4; ++r) {
    float4 o;
    o.x = acc[r][0]; o.y = acc[r][1]; o.z = acc[r][2]; o.w = acc[r][3];
    *(float4 *)(Cb + (m0 + ty * 4 + r) * 256 + n0 + tx * 4) = o;
  }
}

extern "C" void kernel_launch(void* const* d_in, const int* in_sizes, int n_in,
                              void* d_out, int out_size, void* d_ws, size_t ws_size,
                              hipStream_t stream) {
  const float *x  = (const float *)d_in[0];
  const float *Wq = (const float *)d_in[1];
  const float *bq = (const float *)d_in[2];
  const float *Wk = (const float *)d_in[3];
  const float *bk = (const float *)d_in[4];
  const float *Wv = (const float *)d_in[5];
  const float *bv = (const float *)d_in[6];
  const float *Wo = (const float *)d_in[7];
  const float *bo = (const float *)d_in[8];

  float *out = (float *)d_out;                 // [B,S,D]  = 4,194,304 floats
  float *avg = out + 32 * 512 * 256;           // [B,S,S]  = 8,388,608 floats

  // workspace: two 16 MB slots (peak 32 MB)
  float *ws0 = (float *)d_ws;                  // q, then v
  float *ws1 = ws0 + 32 * 512 * 256;           // k, then out_mid

  const dim3 blk(256);
  const dim3 gProj(256, 4);                    // M/64 x N/64

  gemm_proj<<<gProj, blk, 0, stream>>>(x, Wq, bq, ws0, 1);          // q [B,H,S,32]
  gemm_proj<<<gProj, blk, 0, stream>>>(x, Wk, bk, ws1, 1);          // k [B,H,S,32]
  attn_sparsemax<<<dim3(32, 32), blk, 0, stream>>>(ws0, ws1, avg);  // avg [B,S,S]
  gemm_proj<<<gProj, blk, 0, stream>>>(x, Wv, bv, ws0, 0);          // v [B,S,256]
  gemm_av<<<dim3(8, 4, 32), blk, 0, stream>>>(avg, ws0, ws1);       // out_mid
  gemm_proj<<<gProj, blk, 0, stream>>>(ws1, Wo, bo, out, 0);        // final proj
}

// Round 2
// 478.246 us; speedup vs baseline: 1.2047x; 1.2047x over previous
//
#include <hip/hip_runtime.h>
#include <hip/hip_bf16.h>

// Problem constants: B=32, S=512, D=256, H=8, DH=32
#define SCALE_QK 0.17677669529663687f  // 1/sqrt(32)

// C[m,n] = sum_k A[m,k]*W[n,k] + bias[n];  M=16384, N=256, K=256
// mode 0: C stored row-major [m][n] (i.e. [B,S,256])
// mode 1: C stored as q/k layout [b,h,s,e]: b=m>>9, s=m&511, h=n>>5, e=n&31
__global__ __launch_bounds__(256) void gemm_proj(const float *__restrict__ A,
                                                 const float *__restrict__ W,
                                                 const float *__restrict__ bias,
                                                 float *__restrict__ C,
                                                 int mode) {
  __shared__ float As[16][68];
  __shared__ float Ws[16][68];
  const int tid = threadIdx.x;
  const int m0 = blockIdx.x * 64;
  const int n0 = blockIdx.y * 64;
  const int ty = tid >> 4, tx = tid & 15;
  const int lm = tid >> 2, lk4 = (tid & 3) * 4;
  const float *Ald = A + (m0 + lm) * 256 + lk4;
  const float *Wld = W + (n0 + lm) * 256 + lk4;
  float acc[4][4] = {};
  for (int k0 = 0; k0 < 256; k0 += 16) {
    const float4 av = *(const float4 *)(Ald + k0);
    const float4 wv = *(const float4 *)(Wld + k0);
    __syncthreads();
    As[lk4 + 0][lm] = av.x; As[lk4 + 1][lm] = av.y;
    As[lk4 + 2][lm] = av.z; As[lk4 + 3][lm] = av.w;
    Ws[lk4 + 0][lm] = wv.x; Ws[lk4 + 1][lm] = wv.y;
    Ws[lk4 + 2][lm] = wv.z; Ws[lk4 + 3][lm] = wv.w;
    __syncthreads();
#pragma unroll
    for (int kk = 0; kk < 16; ++kk) {
      const float4 a = *(const float4 *)&As[kk][ty * 4];
      const float4 w = *(const float4 *)&Ws[kk][tx * 4];
      const float ar[4] = {a.x, a.y, a.z, a.w};
      const float wr[4] = {w.x, w.y, w.z, w.w};
#pragma unroll
      for (int r = 0; r < 4; ++r)
#pragma unroll
        for (int c = 0; c < 4; ++c) acc[r][c] += ar[r] * wr[c];
    }
  }
  const float4 bs = *(const float4 *)(bias + n0 + tx * 4);
  const float br[4] = {bs.x, bs.y, bs.z, bs.w};
#pragma unroll
  for (int r = 0; r < 4; ++r) {
    const int m = m0 + ty * 4 + r;
    float4 o;
    o.x = acc[r][0] + br[0]; o.y = acc[r][1] + br[1];
    o.z = acc[r][2] + br[2]; o.w = acc[r][3] + br[3];
    if (mode == 0) {
      *(float4 *)(C + m * 256 + n0 + tx * 4) = o;
    } else {
      const int b = m >> 9, s = m & 511;
      const int n = n0 + tx * 4, h = n >> 5, e = n & 31;
      *(float4 *)(C + (((b << 3) + h) * 512 + s) * 32 + e) = o;
    }
  }
}

__device__ __forceinline__ float readlane_f(float v, int lane) {
  return __int_as_float(__builtin_amdgcn_readlane(__float_as_int(v), lane));
}

// Fused scores + diag-mask + sparsemax + head-average.
// Q,K layout [B,H,S,32]. avg output [B,S,S] (already includes the 1/H).
// Block: (s-tile of 16 rows, b). 256 threads = 4 waves; wave w owns rows
// 4w..4w+3; lane l owns t in {4l..4l+3} U {256+4l..256+4l+3} -> each lane
// holds exactly the 8 score elements per row needed for wave-level sparsemax.
// Sparsemax (Michelot): support count via ballot (scalar pipe, wave-uniform);
// the 4 rows' float sums reduced jointly: fold xor16/xor32 (8 ds ops), select
// own group's row, butterfly within 16 lanes (4 ds ops), readlane -> 12 DS ops
// per iteration for all 4 rows (vs 48 for 4 independent butterflies).
__global__ __launch_bounds__(256) void attn_sparsemax(
    const float *__restrict__ Q, const float *__restrict__ Kmat,
    float *__restrict__ avg) {
  __shared__ float kT[16][516];  // [e-half][t], stride 516 keeps writes ~2-way
  __shared__ float qT[32][20];   // [e][r], pre-scaled by 1/sqrt(32)
  const int tid = threadIdx.x;
  const int s0 = blockIdx.x * 16;
  const int b = blockIdx.y;
  const int wave = tid >> 6, lane = tid & 63;
  const bool g0 = (lane & 16) != 0;
  const bool g1 = (lane & 32) != 0;
  float avgacc[4][8] = {};
#pragma unroll 1
  for (int h = 0; h < 8; ++h) {
    const float *qh = Q + (((b << 3) + h) * 512 + s0) * 32;
    const float *kh = Kmat + ((b << 3) + h) * 512 * 32;
    float z[4][8] = {};
#pragma unroll 1
    for (int ph = 0; ph < 2; ++ph) {
      __syncthreads();  // previous LDS consumers done before overwrite
      if (ph == 0 && tid < 128) {
        const float4 v = *(const float4 *)(qh + tid * 4);
        const int r = tid >> 3, e4 = (tid & 7) * 4;
        qT[e4 + 0][r] = v.x * SCALE_QK;
        qT[e4 + 1][r] = v.y * SCALE_QK;
        qT[e4 + 2][r] = v.z * SCALE_QK;
        qT[e4 + 3][r] = v.w * SCALE_QK;
      }
#pragma unroll
      for (int i = 0; i < 8; ++i) {
        const int flat4 = i * 256 + tid;
        const int t = flat4 >> 2, e4 = (flat4 & 3) * 4;
        const float4 v = *(const float4 *)(kh + t * 32 + ph * 16 + e4);
        kT[e4 + 0][t] = v.x; kT[e4 + 1][t] = v.y;
        kT[e4 + 2][t] = v.z; kT[e4 + 3][t] = v.w;
      }
      __syncthreads();
#pragma unroll 4
      for (int e = 0; e < 16; ++e) {
        const float4 qv = *(const float4 *)&qT[ph * 16 + e][wave * 4];
        const float4 ka = *(const float4 *)&kT[e][lane * 4];
        const float4 kb = *(const float4 *)&kT[e][256 + lane * 4];
        const float qr[4] = {qv.x, qv.y, qv.z, qv.w};
        const float kv[8] = {ka.x, ka.y, ka.z, ka.w, kb.x, kb.y, kb.z, kb.w};
#pragma unroll
        for (int r = 0; r < 4; ++r)
#pragma unroll
          for (int j = 0; j < 8; ++j) z[r][j] += qr[r] * kv[j];
      }
    }
    // diag mask (t == s -> -inf surrogate)
#pragma unroll
    for (int r = 0; r < 4; ++r) {
      const int s = s0 + wave * 4 + r;
#pragma unroll
      for (int j = 0; j < 8; ++j) {
        const int t = (j < 4) ? lane * 4 + j : 256 + lane * 4 + (j - 4);
        if (t == s) z[r][j] = -1e30f;
      }
    }
    // joint 4-row sparsemax (Michelot, unified loop; tau0=-1e20 captures all
    // finite entries in iteration 0, so cnt0=511, sum0=sum of finite)
    float tau[4] = {-1e20f, -1e20f, -1e20f, -1e20f};
    int cold[4] = {-1, -1, -1, -1};
    for (int it = 0; it < 16; ++it) {
      float p[4];
      int nc[4];
#pragma unroll
      for (int r = 0; r < 4; ++r) {
        float sm = 0.f;
        int c = 0;
#pragma unroll
        for (int j = 0; j < 8; ++j) {
          const bool pr = z[r][j] > tau[r];
          sm += pr ? z[r][j] : 0.f;
          c += (int)__popcll(__ballot(pr));
        }
        p[r] = sm;
        nc[r] = c;
      }
#pragma unroll
      for (int r = 0; r < 4; ++r) {
        p[r] += __shfl_xor(p[r], 16, 64);
        p[r] += __shfl_xor(p[r], 32, 64);
      }
      float q = g1 ? (g0 ? p[3] : p[2]) : (g0 ? p[1] : p[0]);
      q += __shfl_xor(q, 1, 64);
      q += __shfl_xor(q, 2, 64);
      q += __shfl_xor(q, 4, 64);
      q += __shfl_xor(q, 8, 64);
      float sr[4];
      sr[0] = readlane_f(q, 0);
      sr[1] = readlane_f(q, 16);
      sr[2] = readlane_f(q, 32);
      sr[3] = readlane_f(q, 48);
      if (nc[0] == cold[0] && nc[1] == cold[1] && nc[2] == cold[2] &&
          nc[3] == cold[3])
        break;  // support fixed for all 4 rows -> taus are exact
#pragma unroll
      for (int r = 0; r < 4; ++r) {
        cold[r] = nc[r];
        tau[r] = (sr[r] - 1.f) * __builtin_amdgcn_rcpf((float)nc[r]);
      }
    }
#pragma unroll
    for (int r = 0; r < 4; ++r)
#pragma unroll
      for (int j = 0; j < 8; ++j)
        avgacc[r][j] += fmaxf(z[r][j] - tau[r], 0.f);
  }
#pragma unroll
  for (int r = 0; r < 4; ++r) {
    const int s = s0 + wave * 4 + r;
    float *dst = avg + ((b * 512 + s) << 9);
    float4 o0, o1;
    o0.x = avgacc[r][0] * 0.125f; o0.y = avgacc[r][1] * 0.125f;
    o0.z = avgacc[r][2] * 0.125f; o0.w = avgacc[r][3] * 0.125f;
    o1.x = avgacc[r][4] * 0.125f; o1.y = avgacc[r][5] * 0.125f;
    o1.z = avgacc[r][6] * 0.125f; o1.w = avgacc[r][7] * 0.125f;
    *(float4 *)(dst + lane * 4) = o0;
    *(float4 *)(dst + 256 + lane * 4) = o1;
  }
}

// Batched NN GEMM: C[b] = A[b] (512x512) * V[b] (512x256)
__global__ __launch_bounds__(256) void gemm_av(const float *__restrict__ A,
                                               const float *__restrict__ V,
                                               float *__restrict__ C) {
  __shared__ float As[16][68];
  __shared__ float Bs[16][68];
  const int tid = threadIdx.x;
  const int b = blockIdx.z;
  const int m0 = blockIdx.x * 64, n0 = blockIdx.y * 64;
  const float *Ab = A + b * 512 * 512;
  const float *Vb = V + b * 512 * 256;
  float *Cb = C + b * 512 * 256;
  const int ty = tid >> 4, tx = tid & 15;
  const int lm = tid >> 2, lk4 = (tid & 3) * 4;
  const int lkb = tid >> 4, lnb = (tid & 15) * 4;
  float acc[4][4] = {};
  for (int k0 = 0; k0 < 512; k0 += 16) {
    const float4 av = *(const float4 *)(Ab + (m0 + lm) * 512 + k0 + lk4);
    const float4 bv = *(const float4 *)(Vb + (k0 + lkb) * 256 + n0 + lnb);
    __syncthreads();
    As[lk4 + 0][lm] = av.x; As[lk4 + 1][lm] = av.y;
    As[lk4 + 2][lm] = av.z; As[lk4 + 3][lm] = av.w;
    *(float4 *)&Bs[lkb][lnb] = bv;
    __syncthreads();
#pragma unroll
    for (int kk = 0; kk < 16; ++kk) {
      const float4 a = *(const float4 *)&As[kk][ty * 4];
      const float4 w = *(const float4 *)&Bs[kk][tx * 4];
      const float ar[4] = {a.x, a.y, a.z, a.w};
      const float wr[4] = {w.x, w.y, w.z, w.w};
#pragma unroll
      for (int r = 0; r < 4; ++r)
#pragma unroll
        for (int c = 0; c < 4; ++c) acc[r][c] += ar[r] * wr[c];
    }
  }
#pragma unroll
  for (int r = 0; r < 4; ++r) {
    float4 o;
    o.x = acc[r][0]; o.y = acc[r][1]; o.z = acc[r][2]; o.w = acc[r][3];
    *(float4 *)(Cb + (m0 + ty * 4 + r) * 256 + n0 + tx * 4) = o;
  }
}

extern "C" void kernel_launch(void* const* d_in, const int* in_sizes, int n_in,
                              void* d_out, int out_size, void* d_ws, size_t ws_size,
                              hipStream_t stream) {
  const float *x  = (const float *)d_in[0];
  const float *Wq = (const float *)d_in[1];
  const float *bq = (const float *)d_in[2];
  const float *Wk = (const float *)d_in[3];
  const float *bk = (const float *)d_in[4];
  const float *Wv = (const float *)d_in[5];
  const float *bv = (const float *)d_in[6];
  const float *Wo = (const float *)d_in[7];
  const float *bo = (const float *)d_in[8];

  float *out = (float *)d_out;                 // [B,S,D]  = 4,194,304 floats
  float *avg = out + 32 * 512 * 256;           // [B,S,S]  = 8,388,608 floats

  // workspace: two 16 MB slots (peak 32 MB)
  float *ws0 = (float *)d_ws;                  // q, then v
  float *ws1 = ws0 + 32 * 512 * 256;           // k, then out_mid

  const dim3 blk(256);
  const dim3 gProj(256, 4);                    // M/64 x N/64

  gemm_proj<<<gProj, blk, 0, stream>>>(x, Wq, bq, ws0, 1);          // q [B,H,S,32]
  gemm_proj<<<gProj, blk, 0, stream>>>(x, Wk, bk, ws1, 1);          // k [B,H,S,32]
  attn_sparsemax<<<dim3(32, 32), blk, 0, stream>>>(ws0, ws1, avg);  // avg [B,S,S]
  gemm_proj<<<gProj, blk, 0, stream>>>(x, Wv, bv, ws0, 0);          // v [B,S,256]
  gemm_av<<<dim3(8, 4, 32), blk, 0, stream>>>(avg, ws0, ws1);       // out_mid
  gemm_proj<<<gProj, blk, 0, stream>>>(ws1, Wo, bo, out, 0);        // final proj
}